// Round 5
// baseline (787.600 us; speedup 1.0000x reference)
//
#include <hip/hip_runtime.h>

// Problem constants
#define S_LEN 2048
#define DM    2048
#define HQ_N  16
#define HKV_N 8
#define HD    128

typedef unsigned short u16;
typedef unsigned int   u32;
typedef short bf16x8 __attribute__((ext_vector_type(8)));
typedef float f32x4  __attribute__((ext_vector_type(4)));
typedef u16   u16x8  __attribute__((ext_vector_type(8)));

__device__ __forceinline__ float b2f(u16 u) {
  u32 x = ((u32)u) << 16;
  return __builtin_bit_cast(float, x);
}
__device__ __forceinline__ u16 f2b(float f) {  // RNE
  u32 u = __builtin_bit_cast(u32, f);
  u32 r = u + 0x7fffu + ((u >> 16) & 1u);
  return (u16)(r >> 16);
}

// ---------------- f32 -> bf16 bulk convert (8 elems/thread) ---------------
__global__ void cvt_bf16(const float* __restrict__ src, u16* __restrict__ dst) {
  int id = blockIdx.x * blockDim.x + threadIdx.x;
  float4 a = ((const float4*)src)[id * 2];
  float4 b = ((const float4*)src)[id * 2 + 1];
  u16x8 o;
  o[0] = f2b(a.x); o[1] = f2b(a.y); o[2] = f2b(a.z); o[3] = f2b(a.w);
  o[4] = f2b(b.x); o[5] = f2b(b.y); o[6] = f2b(b.z); o[7] = f2b(b.w);
  ((u16x8*)dst)[id] = o;
}

// ---------------- RoPE tables: cos/sin[t][i], t<2048, i<64 ----------------
__global__ void rope_tables(float* __restrict__ cosT, float* __restrict__ sinT) {
  int id = blockIdx.x * blockDim.x + threadIdx.x;  // 131072
  int t = id >> 6, i = id & 63;
  float inv = (float)pow(10000.0, -(double)(2 * i) / 128.0);
  float ang = (float)t * inv;
  cosT[id] = cosf(ang);
  sinT[id] = sinf(ang);
}

// ---------------- GEMM: C(MxN) = A(MxK) * W(NxK)^T, bf16 in, f32 acc ------
// EPI 1: V-transpose -> Vt[(b*HKV+hk)*HD+d][s] bf16
// EPI 2: head-transpose -> dst[((b*HH+h)*S+s)*HD+d] bf16
// EPI 3: natural f32 (final output)
template <int EPI, int HH>
__global__ __launch_bounds__(256) void gemm_bt(const u16* __restrict__ A,
                                               const u16* __restrict__ W,
                                               void* __restrict__ Cv,
                                               int M, int N, int K) {
  __shared__ alignas(16) u16 As[128 * 32];
  __shared__ alignas(16) u16 Bs[128 * 32];
  const int tid  = threadIdx.x;
  const int lane = tid & 63;
  const int wave = tid >> 6;
  const int wr = (wave >> 1) * 64;  // wave row offset in tile
  const int wc = (wave & 1) * 64;   // wave col offset in tile
  const int bm = blockIdx.y * 128;
  const int bn = blockIdx.x * 128;
  const int r0 = tid >> 2;          // staging row 0..63
  const int c0 = (tid & 3) * 8;     // staging col {0,8,16,24}
  const u16* Ap = A + (size_t)(bm + r0) * K + c0;
  const u16* Wp = W + (size_t)(bn + r0) * K + c0;
  const int cl = lane & 15;
  const int g8 = (lane >> 4) * 8;
  f32x4 acc[4][4] = {};
  for (int k0 = 0; k0 < K; k0 += 32) {
    uint4 a0 = *(const uint4*)(Ap + k0);
    uint4 a1 = *(const uint4*)(Ap + (size_t)64 * K + k0);
    uint4 b0 = *(const uint4*)(Wp + k0);
    uint4 b1 = *(const uint4*)(Wp + (size_t)64 * K + k0);
    __syncthreads();
    *(uint4*)&As[r0 * 32 + c0]        = a0;
    *(uint4*)&As[(r0 + 64) * 32 + c0] = a1;
    *(uint4*)&Bs[r0 * 32 + c0]        = b0;
    *(uint4*)&Bs[(r0 + 64) * 32 + c0] = b1;
    __syncthreads();
    bf16x8 af[4], bfr[4];
#pragma unroll
    for (int m = 0; m < 4; ++m)
      af[m] = *(const bf16x8*)&As[(wr + m * 16 + cl) * 32 + g8];
#pragma unroll
    for (int n = 0; n < 4; ++n)
      bfr[n] = *(const bf16x8*)&Bs[(wc + n * 16 + cl) * 32 + g8];
#pragma unroll
    for (int m = 0; m < 4; ++m)
#pragma unroll
      for (int n = 0; n < 4; ++n)
        acc[m][n] = __builtin_amdgcn_mfma_f32_16x16x32_bf16(af[m], bfr[n], acc[m][n], 0, 0, 0);
  }
  const int g4 = (lane >> 4) * 4;
#pragma unroll
  for (int m = 0; m < 4; ++m)
#pragma unroll
    for (int n = 0; n < 4; ++n)
#pragma unroll
      for (int r = 0; r < 4; ++r) {
        int row = bm + wr + m * 16 + g4 + r;   // M index: b*S + s
        int col = bn + wc + n * 16 + cl;       // N index
        float fv = acc[m][n][r];
        if (EPI == 3) {
          ((float*)Cv)[(size_t)row * N + col] = fv;
        } else if (EPI == 1) {  // col = hkv*128+d -> Vt[(b*HKV+hk)*HD+d][s]
          int bb = row >> 11, s = row & (S_LEN - 1);
          int hk = col >> 7, d = col & (HD - 1);
          ((u16*)Cv)[((size_t)((bb * HKV_N + hk) * HD + d)) * S_LEN + s] = f2b(fv);
        } else {  // EPI 2: col = h*128+d -> dst[((b*HH+h)*S+s)*HD+d]
          int bb = row >> 11, s = row & (S_LEN - 1);
          int h = col >> 7, d = col & (HD - 1);
          ((u16*)Cv)[((size_t)((bb * HH + h) * S_LEN + s)) * HD + d] = f2b(fv);
        }
      }
}

// ---------------- RoPE in-place on [(b*H+h)*S+s][d] bf16 ------------------
__global__ void rope_inplace(u16* __restrict__ buf,
                             const float* __restrict__ cosT,
                             const float* __restrict__ sinT, float scale) {
  int id = blockIdx.x * blockDim.x + threadIdx.x;  // B*H*S*16 threads
  int d0 = (id & 15) * 8;
  int rs = id >> 4;                 // (b*H+h)*S + s
  int s = rs & (S_LEN - 1);
  u16* p = buf + (size_t)rs * HD + d0;
  u16x8 v = *(const u16x8*)p;
  int p0 = d0 >> 1;
  float4 c  = *(const float4*)(cosT + s * 64 + p0);
  float4 sn = *(const float4*)(sinT + s * 64 + p0);
  float cc[4] = {c.x, c.y, c.z, c.w};
  float ss[4] = {sn.x, sn.y, sn.z, sn.w};
  u16x8 o;
#pragma unroll
  for (int j = 0; j < 4; ++j) {
    float x0 = b2f(v[2 * j]), x1 = b2f(v[2 * j + 1]);
    o[2 * j]     = f2b((x0 * cc[j] - x1 * ss[j]) * scale);
    o[2 * j + 1] = f2b((x0 * ss[j] + x1 * cc[j]) * scale);
  }
  *(u16x8*)p = o;
}

// ---------------- Flash attention: 1 wave per 16-row Q tile ---------------
// Q: [(b*HQ+h)*S+s][d] (scale pre-folded), K: [(b*HKV+hk)*S+s][d],
// Vt: [(b*HKV+hk)*HD+d][s], O: natural bf16 [b*S+q][h*HD+d]
__global__ __launch_bounds__(256) void attn_fwd(const u16* __restrict__ Q,
                                                const u16* __restrict__ Kh,
                                                const u16* __restrict__ Vt,
                                                u16* __restrict__ O) {
  __shared__ alignas(16) u16 Plds[4][16 * 32];
  const int wave = threadIdx.x >> 6;
  const int lane = threadIdx.x & 63;
  const int gid = blockIdx.x * 4 + wave;  // 4096 jobs
  const int bh = gid >> 7;                // b*HQ + h
  const int qt = gid & 127;
  const int q0 = qt * 16;
  const int bb = bh >> 4, h = bh & 15;
  const int bkv = bb * HKV_N + (h >> 1);
  const u16* Qp = Q  + ((size_t)bh * S_LEN + q0) * HD;
  const u16* Kp = Kh + (size_t)bkv * S_LEN * HD;
  const u16* Vp = Vt + (size_t)bkv * HD * S_LEN;
  const int cl = lane & 15;
  const int gr = lane >> 4;
  bf16x8 qf[4];
#pragma unroll
  for (int c = 0; c < 4; ++c)
    qf[c] = *(const bf16x8*)&Qp[cl * HD + c * 32 + gr * 8];
  float m[4]    = {-1e30f, -1e30f, -1e30f, -1e30f};
  float lsum[4] = {0.f, 0.f, 0.f, 0.f};
  f32x4 oacc[8] = {};
  const int ntile = (q0 + 47) >> 5;  // 32-key tiles covering keys <= q0+15
  u16* Pw = &Plds[wave][0];
  for (int t = 0; t < ntile; ++t) {
    const int k0 = t * 32;
    f32x4 sc0 = {0.f, 0.f, 0.f, 0.f};
    f32x4 sc1 = {0.f, 0.f, 0.f, 0.f};
#pragma unroll
    for (int c = 0; c < 4; ++c) {
      bf16x8 kf0 = *(const bf16x8*)&Kp[(size_t)(k0 + cl) * HD + c * 32 + gr * 8];
      bf16x8 kf1 = *(const bf16x8*)&Kp[(size_t)(k0 + 16 + cl) * HD + c * 32 + gr * 8];
      sc0 = __builtin_amdgcn_mfma_f32_16x16x32_bf16(qf[c], kf0, sc0, 0, 0, 0);
      sc1 = __builtin_amdgcn_mfma_f32_16x16x32_bf16(qf[c], kf1, sc1, 0, 0, 0);
    }
    float corr[4];
#pragma unroll
    for (int r = 0; r < 4; ++r) {
      const int q = q0 + gr * 4 + r;
      if (k0 + cl > q)      sc0[r] = -1e30f;   // causal mask
      if (k0 + 16 + cl > q) sc1[r] = -1e30f;
      float mx = fmaxf(sc0[r], sc1[r]);
#pragma unroll
      for (int off = 1; off < 16; off <<= 1)
        mx = fmaxf(mx, __shfl_xor(mx, off));
      const float mn = fmaxf(m[r], mx);
      corr[r] = __expf(m[r] - mn);
      const float p0 = __expf(sc0[r] - mn);
      const float p1 = __expf(sc1[r] - mn);
      float rs = p0 + p1;
#pragma unroll
      for (int off = 1; off < 16; off <<= 1)
        rs += __shfl_xor(rs, off);
      lsum[r] = lsum[r] * corr[r] + rs;
      m[r] = mn;
      Pw[(gr * 4 + r) * 32 + cl]      = f2b(p0);
      Pw[(gr * 4 + r) * 32 + 16 + cl] = f2b(p1);
    }
#pragma unroll
    for (int nd = 0; nd < 8; ++nd)
#pragma unroll
      for (int r = 0; r < 4; ++r) oacc[nd][r] *= corr[r];
    // within-wave LDS fence: P writes (all lanes) must land before transposed read
    __builtin_amdgcn_sched_barrier(0);
    asm volatile("s_waitcnt lgkmcnt(0)" ::: "memory");
    __builtin_amdgcn_sched_barrier(0);
    bf16x8 pa = *(const bf16x8*)&Pw[cl * 32 + gr * 8];
#pragma unroll
    for (int nd = 0; nd < 8; ++nd) {
      bf16x8 vf = *(const bf16x8*)&Vp[(size_t)(nd * 16 + cl) * S_LEN + k0 + gr * 8];
      oacc[nd] = __builtin_amdgcn_mfma_f32_16x16x32_bf16(pa, vf, oacc[nd], 0, 0, 0);
    }
  }
#pragma unroll
  for (int r = 0; r < 4; ++r) {
    const int q = q0 + gr * 4 + r;
    const float inv = 1.0f / lsum[r];
#pragma unroll
    for (int nd = 0; nd < 8; ++nd)
      O[(((size_t)bb * S_LEN + q) * HQ_N + h) * HD + nd * 16 + cl] =
          f2b(oacc[nd][r] * inv);
  }
}

// ---------------- launch ---------------------------------------------------
extern "C" void kernel_launch(void* const* d_in, const int* in_sizes, int n_in,
                              void* d_out, int out_size, void* d_ws, size_t ws_size,
                              hipStream_t stream) {
  (void)in_sizes; (void)n_in; (void)out_size; (void)ws_size;
  const float* x  = (const float*)d_in[0];
  const float* wq = (const float*)d_in[1];
  const float* wk = (const float*)d_in[2];
  const float* wv = (const float*)d_in[3];
  const float* wo = (const float*)d_in[4];
  float* out = (float*)d_out;
  char* w = (char*)d_ws;
  // workspace map (bytes), total ~68.2 MB
  u16*  Qh   = (u16*)(w + 0);           // 16,777,216  [(b*16+h)*S+s][d]
  u16*  Kh   = (u16*)(w + 16777216);    //  8,388,608  [(b*8+hk)*S+s][d]
  u16*  Vt   = (u16*)(w + 25165824);    //  8,388,608  [(b*8+hk)*128+d][s]
  u16*  x16  = (u16*)(w + 33554432);    // 16,777,216  (attnout aliases after V gemm)
  u16*  wq16 = (u16*)(w + 50331648);    //  8,388,608  (wo16 aliases after Q gemm)
  u16*  wk16 = (u16*)(w + 58720256);    //  4,194,304
  u16*  wv16 = (u16*)(w + 62914560);    //  4,194,304
  float* cosT = (float*)(w + 67108864); //    524,288
  float* sinT = (float*)(w + 67633152); //    524,288
  u16* wo16 = wq16;                     // alias (wq16 dead after Q gemm)
  u16* attnout = x16;                   // alias (x16 dead after V gemm)

  rope_tables<<<512, 256, 0, stream>>>(cosT, sinT);
  cvt_bf16<<<4096, 256, 0, stream>>>(x,  x16);
  cvt_bf16<<<2048, 256, 0, stream>>>(wq, wq16);
  cvt_bf16<<<1024, 256, 0, stream>>>(wk, wk16);
  cvt_bf16<<<1024, 256, 0, stream>>>(wv, wv16);
  gemm_bt<2, 16><<<dim3(16, 32), 256, 0, stream>>>(x16, wq16, Qh, 4096, 2048, 2048);
  gemm_bt<2, 8> <<<dim3(8, 32),  256, 0, stream>>>(x16, wk16, Kh, 4096, 1024, 2048);
  gemm_bt<1, 8> <<<dim3(8, 32),  256, 0, stream>>>(x16, wv16, Vt, 4096, 1024, 2048);
  cvt_bf16<<<2048, 256, 0, stream>>>(wo, wo16);   // into wq16's space (dead)
  rope_inplace<<<4096, 256, 0, stream>>>(Qh, cosT, sinT, 0.08838834764831845f);
  rope_inplace<<<2048, 256, 0, stream>>>(Kh, cosT, sinT, 1.0f);
  attn_fwd<<<1024, 256, 0, stream>>>(Qh, Kh, Vt, attnout);
  gemm_bt<3, 16><<<dim3(16, 32), 256, 0, stream>>>(attnout, wo16, out, 4096, 2048, 2048);
}